// Round 5
// baseline (893.539 us; speedup 1.0000x reference)
//
#include <hip/hip_runtime.h>

typedef __bf16 bf16;
typedef __bf16 bf16x8 __attribute__((ext_vector_type(8)));
typedef __bf16 bf16x4 __attribute__((ext_vector_type(4)));
typedef __bf16 bf16x2 __attribute__((ext_vector_type(2)));
typedef float  f32x4  __attribute__((ext_vector_type(4)));
typedef float  f32x16 __attribute__((ext_vector_type(16)));

#define SEQ     2048
#define HIDDEN  3584
#define NHEADS  28
#define NKV     4
#define HD      128
#define SCALING 0.08838834764831845f
#define L2E     1.44269504088896341f
#define QSCALE  (SCALING * L2E)

typedef __attribute__((address_space(1))) void gvoid;
typedef __attribute__((address_space(3))) void lvoid;

__device__ __forceinline__ void gl_lds16(const void* g, void* l) {
  __builtin_amdgcn_global_load_lds((gvoid*)g, (lvoid*)l, 16, 0, 0);
}

// counted-vmcnt barrier: loads beyond the oldest N stay in flight across it
#define WAITBAR(N)                                                      \
  do {                                                                  \
    asm volatile("s_waitcnt vmcnt(" #N ") lgkmcnt(0)" ::: "memory");    \
    __builtin_amdgcn_sched_barrier(0);                                  \
    __builtin_amdgcn_s_barrier();                                       \
    __builtin_amdgcn_sched_barrier(0);                                  \
  } while (0)

// ---------------- fp32 -> bf16 convert ----------------
__global__ void f2bf_kernel(const float* __restrict__ in, bf16* __restrict__ out, int n8) {
  int i = blockIdx.x * 256 + threadIdx.x;
  if (i >= n8) return;
  const f32x4* p = (const f32x4*)(in + (size_t)i * 8);
  f32x4 x = p[0], y = p[1];
  bf16x8 o;
  o[0] = (bf16)x[0]; o[1] = (bf16)x[1]; o[2] = (bf16)x[2]; o[3] = (bf16)x[3];
  o[4] = (bf16)y[0]; o[5] = (bf16)y[1]; o[6] = (bf16)y[2]; o[7] = (bf16)y[3];
  *(bf16x8*)(out + (size_t)i * 8) = o;
}

// ---------------- NT GEMM: C[m][n] = sum_k A[m][k] * W[n][k] (+bias) --------
// 128x128 tile, BK=32, 3-buffer LDS pipeline: stage(t+2) || compute(t),
// one raw s_barrier + vmcnt(4) per K-step (no drain-to-zero in steady loop).
template <int MODE>
__global__ __launch_bounds__(256, 3) void gemm_kernel(
    const bf16* __restrict__ A,
    const bf16* __restrict__ W0, const bf16* __restrict__ W1, const bf16* __restrict__ W2,
    const float* __restrict__ b0, const float* __restrict__ b1, const float* __restrict__ b2,
    float* __restrict__ outF,
    bf16* __restrict__ Qb, bf16* __restrict__ Kb, bf16* __restrict__ Vb) {
  __shared__ bf16 sh[3 * 8192];          // 3 bufs x (A 4096 + B 4096) = 48 KiB
  const int tid = threadIdx.x;
  const int w = tid >> 6, lane = tid & 63;
  const int wm = (w >> 1) * 64, wn = (w & 1) * 64;
  const int m0 = blockIdx.y * 128;
  const int n0 = blockIdx.x * 128;
  const int K = HIDDEN;

  const bf16* Bsrc;
  int nbase;
  if (MODE == 0) { Bsrc = W0; nbase = 0; }
  else {
    if (n0 < 3584)      { Bsrc = W0; nbase = 0; }
    else if (n0 < 4096) { Bsrc = W1; nbase = 3584; }
    else                { Bsrc = W2; nbase = 4096; }
  }
  const int bn0 = n0 - nbase;

  f32x4 acc[4][4];
#pragma unroll
  for (int i = 0; i < 4; i++)
#pragma unroll
    for (int j = 0; j < 4; j++) { f32x4 z = {0.f, 0.f, 0.f, 0.f}; acc[i][j] = z; }

  const int srow = lane >> 2;
  const int scol = (lane & 3) * 8;
  const int mr = lane & 15, kq = (lane >> 4) * 8;

  const int c0row = (w * 2 + 0) * 16 + srow;
  const int c1row = (w * 2 + 1) * 16 + srow;
  const bf16* a0 = &A[(size_t)(m0 + c0row) * K + scol];
  const bf16* a1 = &A[(size_t)(m0 + c1row) * K + scol];
  const bf16* w0p = &Bsrc[(size_t)(bn0 + c0row) * K + scol];
  const bf16* w1p = &Bsrc[(size_t)(bn0 + c1row) * K + scol];
  const int l0 = (w * 2 + 0) * 512;
  const int l1 = (w * 2 + 1) * 512;

  auto STAGE = [&](int t, int bufbase) {
    const int ko = t * 32;
    gl_lds16(a0 + ko,  &sh[bufbase + l0]);
    gl_lds16(w0p + ko, &sh[bufbase + 4096 + l0]);
    gl_lds16(a1 + ko,  &sh[bufbase + l1]);
    gl_lds16(w1p + ko, &sh[bufbase + 4096 + l1]);
  };
  auto COMPUTE = [&](int bufbase) {
    bf16x8 a[4], b[4];
#pragma unroll
    for (int i = 0; i < 4; i++) a[i] = *(const bf16x8*)&sh[bufbase + (wm + i * 16 + mr) * 32 + kq];
#pragma unroll
    for (int j = 0; j < 4; j++) b[j] = *(const bf16x8*)&sh[bufbase + 4096 + (wn + j * 16 + mr) * 32 + kq];
#pragma unroll
    for (int i = 0; i < 4; i++)
#pragma unroll
      for (int j = 0; j < 4; j++)
        acc[i][j] = __builtin_amdgcn_mfma_f32_16x16x32_bf16(a[i], b[j], acc[i][j], 0, 0, 0);
  };

  STAGE(0, 0);
  STAGE(1, 8192);
  WAITBAR(4);

#pragma unroll 1
  for (int tt = 0; tt < 36; ++tt) {
    const int t0 = tt * 3;
    STAGE(t0 + 2, 16384); COMPUTE(0);     WAITBAR(4);
    STAGE(t0 + 3, 0);     COMPUTE(8192);  WAITBAR(4);
    STAGE(t0 + 4, 8192);  COMPUTE(16384); WAITBAR(4);
  }
  STAGE(110, 16384); COMPUTE(0);     WAITBAR(4);
  STAGE(111, 0);     COMPUTE(8192);  WAITBAR(4);
  COMPUTE(16384);    WAITBAR(0);
  COMPUTE(0);

  const int quad = lane >> 4, col = lane & 15;
  if (MODE == 0) {
#pragma unroll
    for (int i = 0; i < 4; i++)
#pragma unroll
      for (int j = 0; j < 4; j++) {
        int n = n0 + wn + j * 16 + col;
#pragma unroll
        for (int r = 0; r < 4; r++) {
          int m = m0 + wm + i * 16 + quad * 4 + r;
          outF[(size_t)m * 3584 + n] = acc[i][j][r];
        }
      }
  } else {
    bf16* dst; int H; const float* bias; float mult;
    if (n0 < 3584)      { dst = Qb; H = NHEADS; bias = b0; mult = QSCALE; }
    else if (n0 < 4096) { dst = Kb; H = NKV;    bias = b1; mult = 1.0f; }
    else                { dst = Vb; H = NKV;    bias = b2; mult = 1.0f; }
    const int hh = bn0 >> 7;
    float bb[4];
#pragma unroll
    for (int j = 0; j < 4; j++) bb[j] = bias[bn0 + wn + j * 16 + col];
    __syncthreads();
#pragma unroll
    for (int i = 0; i < 4; i++)
#pragma unroll
      for (int j = 0; j < 4; j++)
#pragma unroll
        for (int r = 0; r < 4; r++)
          sh[(wm + i * 16 + quad * 4 + r) * 136 + wn + j * 16 + col] =
              (bf16)((acc[i][j][r] + bb[j]) * mult);
    __syncthreads();
    const int drow = tid >> 4, dcol = (tid & 15) * 8;
#pragma unroll
    for (int cc = 0; cc < 8; cc++) {
      int row = cc * 16 + drow;
      int m = m0 + row;
      int bidx = m >> 11, s = m & 2047;
      bf16x8 v = *(const bf16x8*)&sh[row * 136 + dcol];
      *(bf16x8*)&dst[(((size_t)bidx * H + hh) * SEQ + s) * HD + dcol] = v;
    }
  }
}

// ---------------- RoPE (in place, bf16) ----------------
__global__ void rope_kernel(bf16* __restrict__ X, const float* __restrict__ cosp,
                            const float* __restrict__ sinp, int nheads) {
  int idx = blockIdx.x * 256 + threadIdx.x;
  int dg = idx & 15;
  int s = (idx >> 4) & 2047;
  int bh = idx >> 15;
  int b = bh / nheads;
  int d = dg * 4;
  f32x4 c = *(const f32x4*)&cosp[((size_t)b * SEQ + s) * HD + d];
  f32x4 sn = *(const f32x4*)&sinp[((size_t)b * SEQ + s) * HD + d];
  bf16* p = X + ((size_t)bh * SEQ + s) * HD + d;
  bf16x4 lo = *(bf16x4*)p;
  bf16x4 hi = *(bf16x4*)(p + 64);
  bf16x4 nlo, nhi;
#pragma unroll
  for (int i = 0; i < 4; i++) {
    float l = (float)lo[i], h = (float)hi[i];
    nlo[i] = (bf16)(l * c[i] - h * sn[i]);
    nhi[i] = (bf16)(h * c[i] + l * sn[i]);
  }
  *(bf16x4*)p = nlo;
  *(bf16x4*)(p + 64) = nhi;
}

// ---------------- V transpose per head: [S][D] -> [D][S] ----------------
__global__ void transpose_kernel(const bf16* __restrict__ V, bf16* __restrict__ Vt) {
  __shared__ bf16 t[32][33];
  int head = blockIdx.z;
  int s0 = blockIdx.x * 32, d0 = blockIdx.y * 32;
  const bf16* src = V + (size_t)head * SEQ * HD;
  bf16* dst = Vt + (size_t)head * HD * SEQ;
#pragma unroll
  for (int i = 0; i < 4; i++)
    t[threadIdx.y + i * 8][threadIdx.x] =
        src[(size_t)(s0 + threadIdx.y + i * 8) * HD + d0 + threadIdx.x];
  __syncthreads();
#pragma unroll
  for (int i = 0; i < 4; i++)
    dst[(size_t)(d0 + threadIdx.y + i * 8) * SEQ + s0 + threadIdx.x] =
        t[threadIdx.x][threadIdx.y + i * 8];
}

__device__ __forceinline__ unsigned pkbf(float x, float y) {
  bf16x2 t; t[0] = (bf16)x; t[1] = (bf16)y;
  return __builtin_bit_cast(unsigned, t);
}

// ---------------- Flash attention, 32x32 MFMA S^T, 8-wave blocks -------------
// grid (8, 28, 2), x reversed (heavy q-tiles first); block 512 = 8 waves.
// Wave w owns 32 q rows [q0+32w, q0+32w+32) (round-3 verified inner loop).
// 8 waves share each staged K/V tile -> staging per wave halved, 16 waves/CU.
// Defer-max: skip o-rescale when __all(tm <= m+8). K/V double-buffered,
// async global_load_lds staging with inverse-swizzled source, 1 barrier/tile.
__global__ __launch_bounds__(512, 4) void flash_kernel(
    const bf16* __restrict__ Q, const bf16* __restrict__ K,
    const bf16* __restrict__ Vt, bf16* __restrict__ attn) {
  __shared__ bf16 Ks[2][64 * 128];   // [key][d], chunk-XOR-swizzled
  __shared__ bf16 Vs[2][128 * 64];   // [d][key], chunk-XOR-swizzled

  const int tid = threadIdx.x, w = tid >> 6, lane = tid & 63;
  const int col = lane & 31, hi = lane >> 5;
  const int rsw = col & 7;
  const int qt = (int)gridDim.x - 1 - (int)blockIdx.x;
  const int q0 = qt * 256;
  const int h = blockIdx.y, b = blockIdx.z;
  const int kvh = h / (NHEADS / NKV);
  const int qw = q0 + w * 32;
  const bf16* Qg = Q + (((size_t)b * NHEADS + h) * SEQ + qw) * HD;
  const bf16* Kg = K + ((size_t)b * NKV + kvh) * SEQ * HD;
  const bf16* Vg = Vt + ((size_t)b * NKV + kvh) * HD * SEQ;

  // Q B-fragments: n = q = col, k(d) = kc*16 + hi*8 + 0..7
  bf16x8 aq[8];
#pragma unroll
  for (int kc = 0; kc < 8; kc++)
    aq[kc] = *(const bf16x8*)&Qg[(size_t)col * HD + kc * 16 + hi * 8];

  // staging: call i stages LDS chunk ch=(i*8+w)*64+lane (16B chunks, 1024 total)
  // LDS holds X[r][c ^ (r&7)] at linear chunk (r,c) -> global src chunk c^(r&7).
  int ksrc[2], vsrc[2], ldsOff[2];
#pragma unroll
  for (int i = 0; i < 2; i++) {
    int ch = (i * 8 + w) * 64 + lane;
    int r = ch >> 4, c = ch & 15;                 // K: 16 chunks per 128-elem row
    ksrc[i] = r * HD + ((c ^ (r & 7)) * 8);
    int rv = ch >> 3, cv = ch & 7;                // V: 8 chunks per 64-elem row
    vsrc[i] = rv * SEQ + ((cv ^ (rv & 7)) * 8);
    ldsOff[i] = (i * 8 + w) * 512;                // wave-uniform dest, elements
  }

  f32x16 o[4];
#pragma unroll
  for (int d = 0; d < 4; d++)
#pragma unroll
    for (int r = 0; r < 16; r++) o[d][r] = 0.f;
  float mi = -1e30f, li = 0.f;
  const int myq = qw + col;
  const int nkt = qt * 4 + 4;

  // prologue: stage tile 0 -> buf 0
#pragma unroll
  for (int i = 0; i < 2; i++) {
    gl_lds16(Kg + ksrc[i], &Ks[0][ldsOff[i]]);
    gl_lds16(Vg + vsrc[i], &Vs[0][ldsOff[i]]);
  }
  asm volatile("s_waitcnt vmcnt(0)" ::: "memory");
  __syncthreads();

  for (int kt = 0; kt < nkt; kt++) {
    const int kt0 = kt * 64;
    const int cur = kt & 1;
    if (kt + 1 < nkt) {                       // async prefetch next tile
      const bf16* kg = Kg + (size_t)(kt0 + 64) * HD;
      const bf16* vg = Vg + (kt0 + 64);
#pragma unroll
      for (int i = 0; i < 2; i++) {
        gl_lds16(kg + ksrc[i], &Ks[cur ^ 1][ldsOff[i]]);
        gl_lds16(vg + vsrc[i], &Vs[cur ^ 1][ldsOff[i]]);
      }
    }
    if (kt0 <= qw + 31) {                     // wave-level causal tile skip
      // S^T = K Q^T: per kb, lane row = kb*32+col (key), cols = q
      f32x16 s[2];
#pragma unroll
      for (int kb = 0; kb < 2; kb++) {
#pragma unroll
        for (int r = 0; r < 16; r++) s[kb][r] = 0.f;
        const bf16* kbase = &Ks[cur][(kb * 32 + col) * 128];
#pragma unroll
        for (int kc = 0; kc < 8; kc++) {
          bf16x8 ak = *(const bf16x8*)&kbase[((kc * 2 + hi) ^ rsw) * 8];
          s[kb] = __builtin_amdgcn_mfma_f32_32x32x16_bf16(ak, aq[kc], s[kb], 0, 0, 0);
        }
      }
      if (kt0 + 63 > qw) {                    // diagonal tiles: mask
#pragma unroll
        for (int kb = 0; kb < 2; kb++)
#pragma unroll
          for (int r = 0; r < 16; r++) {
            int key = kt0 + kb * 32 + (r & 3) + 8 * (r >> 2) + 4 * hi;
            if (key > myq) s[kb][r] = -1e30f;
          }
      }
      // row max: 31 in-lane + 1 shuffle (lane pair l / l+32 share q)
      float tm = -1e30f;
#pragma unroll
      for (int kb = 0; kb < 2; kb++)
#pragma unroll
        for (int r = 0; r < 16; r++) tm = fmaxf(tm, s[kb][r]);
      tm = fmaxf(tm, __shfl_xor(tm, 32, 64));
      if (!__all(tm <= mi + 8.0f)) {          // defer-max: rescale only on growth
        float mnew = fmaxf(mi, tm);
        float alpha = exp2f(mi - mnew);
        li *= alpha;
#pragma unroll
        for (int d = 0; d < 4; d++)
#pragma unroll
          for (int r = 0; r < 16; r++) o[d][r] *= alpha;
        mi = mnew;
      }
      float p[32];
      float rs = 0.f;
#pragma unroll
      for (int kb = 0; kb < 2; kb++)
#pragma unroll
        for (int r = 0; r < 16; r++) {
          float e = exp2f(s[kb][r] - mi);
          p[kb * 16 + r] = e;
          rs += e;
        }
      li += rs;
      // O^T += V^T P^T; P B-frag built in-register via shfl_xor(32) exchange
#pragma unroll
      for (int ks = 0; ks < 4; ks++) {
        const int pb = ks * 8;
        unsigned A = pkbf(p[pb + 0], p[pb + 1]), B = pkbf(p[pb + 2], p[pb + 3]);
        unsigned C = pkbf(p[pb + 4], p[pb + 5]), D = pkbf(p[pb + 6], p[pb + 7]);
        unsigned Ax = __shfl_xor(A, 32, 64);
        unsigned Bx = __shfl_xor(B, 32, 64);
        unsigned Cx = __shfl_xor(C, 32, 64);
        unsigned Dx = __shfl_xor(D, 32, 64);
        union { bf16x8 v; unsigned u[4]; } pf;
        pf.u[0] = hi ? Cx : A;
        pf.u[1] = hi ? Dx : B;
        pf.u[2] = hi ? C : Ax;
        pf.u[3] = hi ? D : Bx;
#pragma unroll
        for (int db = 0; db < 4; db++) {
          const bf16* vbase = &Vs[cur][(db * 32 + col) * 64];
          bf16x8 av = *(const bf16x8*)&vbase[((ks * 2 + hi) ^ rsw) * 8];
          o[db] = __builtin_amdgcn_mfma_f32_32x32x16_bf16(av, pf.v, o[db], 0, 0, 0);
        }
      }
    }
    asm volatile("s_waitcnt vmcnt(0)" ::: "memory");
    __syncthreads();
  }

  // epilogue: finish l across lane pair, store O^T
  li += __shfl_xor(li, 32, 64);
  float rinv = 1.0f / li;
  bf16* dst = attn + ((size_t)b * SEQ + qw + col) * HIDDEN + h * HD;
#pragma unroll
  for (int db = 0; db < 4; db++)
#pragma unroll
    for (int rr = 0; rr < 4; rr++) {
      bf16x4 ob;
#pragma unroll
      for (int j = 0; j < 4; j++) ob[j] = (bf16)(o[db][rr * 4 + j] * rinv);
      *(bf16x4*)&dst[db * 32 + rr * 8 + hi * 4] = ob;
    }
}

extern "C" void kernel_launch(void* const* d_in, const int* in_sizes, int n_in,
                              void* d_out, int out_size, void* d_ws, size_t ws_size,
                              hipStream_t stream) {
  const float* hidden = (const float*)d_in[0];
  const float* cosp   = (const float*)d_in[1];
  const float* sinp   = (const float*)d_in[2];
  const float* Wq = (const float*)d_in[4];
  const float* bq = (const float*)d_in[5];
  const float* Wk = (const float*)d_in[6];
  const float* bk = (const float*)d_in[7];
  const float* Wv = (const float*)d_in[8];
  const float* bv = (const float*)d_in[9];
  const float* Wo = (const float*)d_in[10];
  float* out = (float*)d_out;

  char* ws = (char*)d_ws;
  size_t off = 0;
  auto alloc = [&](size_t bytes) {
    char* p = ws + off;
    off += (bytes + 255) & ~(size_t)255;
    return p;
  };
  const size_t M = 4096;
  bf16* hb  = (bf16*)alloc(M * HIDDEN * 2);
  bf16* wqb = (bf16*)alloc((size_t)3584 * 3584 * 2);
  bf16* wkb = (bf16*)alloc((size_t)512 * 3584 * 2);
  bf16* wvb = (bf16*)alloc((size_t)512 * 3584 * 2);
  bf16* wob = (bf16*)alloc((size_t)3584 * 3584 * 2);
  bf16* Qb  = (bf16*)alloc((size_t)2 * NHEADS * SEQ * HD * 2);
  bf16* Kb  = (bf16*)alloc((size_t)2 * NKV * SEQ * HD * 2);
  bf16* Vb  = (bf16*)alloc((size_t)2 * NKV * SEQ * HD * 2);
  bf16* Vt  = (bf16*)alloc((size_t)2 * NKV * SEQ * HD * 2);
  bf16* attn = hb;  // hidden dead after QKV GEMM

  f2bf_kernel<<<(4096 * 3584 / 8 + 255) / 256, 256, 0, stream>>>(hidden, hb, 4096 * 3584 / 8);
  f2bf_kernel<<<(3584 * 3584 / 8 + 255) / 256, 256, 0, stream>>>(Wq, wqb, 3584 * 3584 / 8);
  f2bf_kernel<<<(512 * 3584 / 8 + 255) / 256, 256, 0, stream>>>(Wk, wkb, 512 * 3584 / 8);
  f2bf_kernel<<<(512 * 3584 / 8 + 255) / 256, 256, 0, stream>>>(Wv, wvb, 512 * 3584 / 8);
  f2bf_kernel<<<(3584 * 3584 / 8 + 255) / 256, 256, 0, stream>>>(Wo, wob, 3584 * 3584 / 8);

  gemm_kernel<1><<<dim3(36, 32), 256, 0, stream>>>(hb, wqb, wkb, wvb, bq, bk, bv,
                                                   nullptr, Qb, Kb, Vb);
  rope_kernel<<<2 * NHEADS * SEQ * 16 / 256, 256, 0, stream>>>(Qb, cosp, sinp, NHEADS);
  rope_kernel<<<2 * NKV * SEQ * 16 / 256, 256, 0, stream>>>(Kb, cosp, sinp, NKV);
  transpose_kernel<<<dim3(64, 4, 8), dim3(32, 8), 0, stream>>>(Vb, Vt);
  flash_kernel<<<dim3(8, 28, 2), 512, 0, stream>>>(Qb, Kb, Vt, attn);
  gemm_kernel<0><<<dim3(28, 32), 256, 0, stream>>>(attn, wob, nullptr, nullptr,
                                                   nullptr, nullptr, nullptr,
                                                   out, nullptr, nullptr, nullptr);
}

// Round 6
// 711.782 us; speedup vs baseline: 1.2554x; 1.2554x over previous
//
#include <hip/hip_runtime.h>

typedef __bf16 bf16;
typedef __bf16 bf16x8 __attribute__((ext_vector_type(8)));
typedef __bf16 bf16x4 __attribute__((ext_vector_type(4)));
typedef __bf16 bf16x2 __attribute__((ext_vector_type(2)));
typedef float  f32x4  __attribute__((ext_vector_type(4)));
typedef float  f32x16 __attribute__((ext_vector_type(16)));

#define SEQ     2048
#define HIDDEN  3584
#define NHEADS  28
#define NKV     4
#define HD      128
#define SCALING 0.08838834764831845f
#define L2E     1.44269504088896341f
#define QSCALE  (SCALING * L2E)

typedef __attribute__((address_space(1))) void gvoid;
typedef __attribute__((address_space(3))) void lvoid;

__device__ __forceinline__ void gl_lds16(const void* g, void* l) {
  __builtin_amdgcn_global_load_lds((gvoid*)g, (lvoid*)l, 16, 0, 0);
}

// counted-vmcnt barrier: loads beyond the oldest N stay in flight across it
#define WAITBAR(N)                                                      \
  do {                                                                  \
    asm volatile("s_waitcnt vmcnt(" #N ") lgkmcnt(0)" ::: "memory");    \
    __builtin_amdgcn_sched_barrier(0);                                  \
    __builtin_amdgcn_s_barrier();                                       \
    __builtin_amdgcn_sched_barrier(0);                                  \
  } while (0)

// ---------------- fp32 -> bf16 convert ----------------
__global__ void f2bf_kernel(const float* __restrict__ in, bf16* __restrict__ out, int n8) {
  int i = blockIdx.x * 256 + threadIdx.x;
  if (i >= n8) return;
  const f32x4* p = (const f32x4*)(in + (size_t)i * 8);
  f32x4 x = p[0], y = p[1];
  bf16x8 o;
  o[0] = (bf16)x[0]; o[1] = (bf16)x[1]; o[2] = (bf16)x[2]; o[3] = (bf16)x[3];
  o[4] = (bf16)y[0]; o[5] = (bf16)y[1]; o[6] = (bf16)y[2]; o[7] = (bf16)y[3];
  *(bf16x8*)(out + (size_t)i * 8) = o;
}

// ---------------- NT GEMM: C[m][n] = sum_k A[m][k] * W[n][k] (+bias) --------
// 128x128 tile, BK=32, 3-buffer LDS pipeline: stage(t+2) || compute(t),
// one raw s_barrier + vmcnt(4) per K-step (no drain-to-zero in steady loop).
// MODE 1 epilogue: fused bias+scale+RoPE for Q/K; fused transpose for V (-> Vt).
template <int MODE>
__global__ __launch_bounds__(256, 3) void gemm_kernel(
    const bf16* __restrict__ A,
    const bf16* __restrict__ W0, const bf16* __restrict__ W1, const bf16* __restrict__ W2,
    const float* __restrict__ b0, const float* __restrict__ b1, const float* __restrict__ b2,
    const float* __restrict__ cosp, const float* __restrict__ sinp,
    float* __restrict__ outF,
    bf16* __restrict__ Qb, bf16* __restrict__ Kb, bf16* __restrict__ Vtb) {
  __shared__ bf16 sh[3 * 8192];          // 3 bufs x (A 4096 + B 4096) = 48 KiB
  const int tid = threadIdx.x;
  const int w = tid >> 6, lane = tid & 63;
  const int wm = (w >> 1) * 64, wn = (w & 1) * 64;
  const int m0 = blockIdx.y * 128;
  const int n0 = blockIdx.x * 128;
  const int K = HIDDEN;

  const bf16* Bsrc;
  int nbase;
  if (MODE == 0) { Bsrc = W0; nbase = 0; }
  else {
    if (n0 < 3584)      { Bsrc = W0; nbase = 0; }
    else if (n0 < 4096) { Bsrc = W1; nbase = 3584; }
    else                { Bsrc = W2; nbase = 4096; }
  }
  const int bn0 = n0 - nbase;

  f32x4 acc[4][4];
#pragma unroll
  for (int i = 0; i < 4; i++)
#pragma unroll
    for (int j = 0; j < 4; j++) { f32x4 z = {0.f, 0.f, 0.f, 0.f}; acc[i][j] = z; }

  const int srow = lane >> 2;
  const int scol = (lane & 3) * 8;
  const int mr = lane & 15, kq = (lane >> 4) * 8;

  const int c0row = (w * 2 + 0) * 16 + srow;
  const int c1row = (w * 2 + 1) * 16 + srow;
  const bf16* a0 = &A[(size_t)(m0 + c0row) * K + scol];
  const bf16* a1 = &A[(size_t)(m0 + c1row) * K + scol];
  const bf16* w0p = &Bsrc[(size_t)(bn0 + c0row) * K + scol];
  const bf16* w1p = &Bsrc[(size_t)(bn0 + c1row) * K + scol];
  const int l0 = (w * 2 + 0) * 512;
  const int l1 = (w * 2 + 1) * 512;

  auto STAGE = [&](int t, int bufbase) {
    const int ko = t * 32;
    gl_lds16(a0 + ko,  &sh[bufbase + l0]);
    gl_lds16(w0p + ko, &sh[bufbase + 4096 + l0]);
    gl_lds16(a1 + ko,  &sh[bufbase + l1]);
    gl_lds16(w1p + ko, &sh[bufbase + 4096 + l1]);
  };
  auto COMPUTE = [&](int bufbase) {
    bf16x8 a[4], b[4];
#pragma unroll
    for (int i = 0; i < 4; i++) a[i] = *(const bf16x8*)&sh[bufbase + (wm + i * 16 + mr) * 32 + kq];
#pragma unroll
    for (int j = 0; j < 4; j++) b[j] = *(const bf16x8*)&sh[bufbase + 4096 + (wn + j * 16 + mr) * 32 + kq];
#pragma unroll
    for (int i = 0; i < 4; i++)
#pragma unroll
      for (int j = 0; j < 4; j++)
        acc[i][j] = __builtin_amdgcn_mfma_f32_16x16x32_bf16(a[i], b[j], acc[i][j], 0, 0, 0);
  };

  STAGE(0, 0);
  STAGE(1, 8192);
  WAITBAR(4);

#pragma unroll 1
  for (int tt = 0; tt < 36; ++tt) {
    const int t0 = tt * 3;
    STAGE(t0 + 2, 16384); COMPUTE(0);     WAITBAR(4);
    STAGE(t0 + 3, 0);     COMPUTE(8192);  WAITBAR(4);
    STAGE(t0 + 4, 8192);  COMPUTE(16384); WAITBAR(4);
  }
  STAGE(110, 16384); COMPUTE(0);     WAITBAR(4);
  STAGE(111, 0);     COMPUTE(8192);  WAITBAR(4);
  COMPUTE(16384);    WAITBAR(0);
  COMPUTE(0);

  const int quad = lane >> 4, col = lane & 15;
  if (MODE == 0) {
#pragma unroll
    for (int i = 0; i < 4; i++)
#pragma unroll
      for (int j = 0; j < 4; j++) {
        int n = n0 + wn + j * 16 + col;
#pragma unroll
        for (int r = 0; r < 4; r++) {
          int m = m0 + wm + i * 16 + quad * 4 + r;
          outF[(size_t)m * 3584 + n] = acc[i][j][r];
        }
      }
  } else {
    // kind 0: Q or K (rope); kind 1: V (transpose -> Vt)
    int kind; bf16* dst; int H; const float* bias; float mult;
    if (n0 < 3584)      { kind = 0; dst = Qb;  H = NHEADS; bias = b0; mult = QSCALE; }
    else if (n0 < 4096) { kind = 0; dst = Kb;  H = NKV;    bias = b1; mult = 1.0f; }
    else                { kind = 1; dst = Vtb; H = NKV;    bias = b2; mult = 1.0f; }
    const int hh = bn0 >> 7;
    const int bidx = m0 >> 11;
    const int sbase = m0 & 2047;
    float bb[4];
#pragma unroll
    for (int j = 0; j < 4; j++) bb[j] = bias[bn0 + wn + j * 16 + col];
    __syncthreads();                       // all waves done with K-loop LDS
    // stage C tile [m(s)][d] into LDS (stride 136 elems, 16B-aligned rows)
#pragma unroll
    for (int i = 0; i < 4; i++)
#pragma unroll
      for (int j = 0; j < 4; j++)
#pragma unroll
        for (int r = 0; r < 4; r++)
          sh[(wm + i * 16 + quad * 4 + r) * 136 + wn + j * 16 + col] =
              (bf16)((acc[i][j][r] + bb[j]) * mult);
    __syncthreads();
    const int drow = tid >> 4, dcol = (tid & 15) * 8;
    if (kind == 0) {
      // fused RoPE: x[d]*cos - x[d^64]*sin (d<64) / x[d]*cos + x[d^64]*sin
      // cos[d] == cos[d&63] (emb = concat(freqs, freqs))
      const float sgn = (dcol < 64) ? -1.f : 1.f;
#pragma unroll
      for (int cc = 0; cc < 8; cc++) {
        int row = cc * 16 + drow;
        int srow2 = sbase + row;
        bf16x8 x  = *(const bf16x8*)&sh[row * 136 + dcol];
        bf16x8 xp = *(const bf16x8*)&sh[row * 136 + (dcol ^ 64)];
        const float* cp = &cosp[((size_t)bidx * SEQ + srow2) * HD + (dcol & 63)];
        const float* sp = &sinp[((size_t)bidx * SEQ + srow2) * HD + (dcol & 63)];
        f32x4 c0 = *(const f32x4*)cp, c1 = *(const f32x4*)(cp + 4);
        f32x4 s0 = *(const f32x4*)sp, s1 = *(const f32x4*)(sp + 4);
        bf16x8 o8;
#pragma unroll
        for (int k = 0; k < 8; k++) {
          float cv = (k < 4) ? c0[k] : c1[k - 4];
          float sv = (k < 4) ? s0[k] : s1[k - 4];
          o8[k] = (bf16)((float)x[k] * cv + sgn * (float)xp[k] * sv);
        }
        *(bf16x8*)&dst[(((size_t)bidx * H + hh) * SEQ + srow2) * HD + dcol] = o8;
      }
    } else {
      // fused transpose: Vt[(bidx*NKV+hh)*HD + d][sbase + s] ; coalesced rows
#pragma unroll
      for (int cc = 0; cc < 8; cc++) {
        int d = cc * 16 + drow;
        bf16x8 o8;
#pragma unroll
        for (int r = 0; r < 8; r++) o8[r] = sh[(dcol + r) * 136 + d];
        *(bf16x8*)&dst[(((size_t)bidx * H + hh) * HD + d) * SEQ + sbase + dcol] = o8;
      }
    }
  }
}

__device__ __forceinline__ unsigned pkbf(float x, float y) {
  bf16x2 t; t[0] = (bf16)x; t[1] = (bf16)y;
  return __builtin_bit_cast(unsigned, t);
}

// ---------------- Flash attention, 32x32 MFMA S^T formulation ----------------
// grid (S/128, 28, 2), x reversed (heavy q-tiles first); block 256 = 4 waves.
// Wave w owns q rows [q0+32w, q0+32w+32); lane's q = lane&31. (round-3 verified
// structure) + defer-max (T13) + s_setprio around MFMA clusters (T5).
__global__ __launch_bounds__(256, 2) void flash_kernel(
    const bf16* __restrict__ Q, const bf16* __restrict__ K,
    const bf16* __restrict__ Vt, bf16* __restrict__ attn) {
  __shared__ bf16 Ks[2][64 * 128];   // [key][d], chunk-XOR-swizzled
  __shared__ bf16 Vs[2][128 * 64];   // [d][key], chunk-XOR-swizzled

  const int tid = threadIdx.x, w = tid >> 6, lane = tid & 63;
  const int col = lane & 31, hi = lane >> 5;
  const int rsw = col & 7;
  const int qt = (int)gridDim.x - 1 - (int)blockIdx.x;
  const int q0 = qt * 128;
  const int h = blockIdx.y, b = blockIdx.z;
  const int kvh = h / (NHEADS / NKV);
  const int qw = q0 + w * 32;
  const bf16* Qg = Q + (((size_t)b * NHEADS + h) * SEQ + qw) * HD;
  const bf16* Kg = K + ((size_t)b * NKV + kvh) * SEQ * HD;
  const bf16* Vg = Vt + ((size_t)b * NKV + kvh) * HD * SEQ;

  bf16x8 aq[8];
#pragma unroll
  for (int kc = 0; kc < 8; kc++)
    aq[kc] = *(const bf16x8*)&Qg[(size_t)col * HD + kc * 16 + hi * 8];

  int ksrc[4], vsrc[4], ldsOff[4];
#pragma unroll
  for (int i = 0; i < 4; i++) {
    int ch = (i * 4 + w) * 64 + lane;
    int r = ch >> 4, c = ch & 15;
    ksrc[i] = r * HD + ((c ^ (r & 7)) * 8);
    int rv = ch >> 3, cv = ch & 7;
    vsrc[i] = rv * SEQ + ((cv ^ (rv & 7)) * 8);
    ldsOff[i] = (i * 4 + w) * 512;
  }

  f32x16 o[4];
#pragma unroll
  for (int d = 0; d < 4; d++)
#pragma unroll
    for (int r = 0; r < 16; r++) o[d][r] = 0.f;
  float mi = -1e30f, li = 0.f;
  const int myq = qw + col;
  const int nkt = q0 / 64 + 2;

#pragma unroll
  for (int i = 0; i < 4; i++) {
    gl_lds16(Kg + ksrc[i], &Ks[0][ldsOff[i]]);
    gl_lds16(Vg + vsrc[i], &Vs[0][ldsOff[i]]);
  }
  asm volatile("s_waitcnt vmcnt(0)" ::: "memory");
  __syncthreads();

  for (int kt = 0; kt < nkt; kt++) {
    const int kt0 = kt * 64;
    const int cur = kt & 1;
    if (kt + 1 < nkt) {
      const bf16* kg = Kg + (size_t)(kt0 + 64) * HD;
      const bf16* vg = Vg + (kt0 + 64);
#pragma unroll
      for (int i = 0; i < 4; i++) {
        gl_lds16(kg + ksrc[i], &Ks[cur ^ 1][ldsOff[i]]);
        gl_lds16(vg + vsrc[i], &Vs[cur ^ 1][ldsOff[i]]);
      }
    }
    if (kt0 <= qw + 31) {
      f32x16 s[2];
      __builtin_amdgcn_s_setprio(1);
#pragma unroll
      for (int kb = 0; kb < 2; kb++) {
#pragma unroll
        for (int r = 0; r < 16; r++) s[kb][r] = 0.f;
        const bf16* kbase = &Ks[cur][(kb * 32 + col) * 128];
#pragma unroll
        for (int kc = 0; kc < 8; kc++) {
          bf16x8 ak = *(const bf16x8*)&kbase[((kc * 2 + hi) ^ rsw) * 8];
          s[kb] = __builtin_amdgcn_mfma_f32_32x32x16_bf16(ak, aq[kc], s[kb], 0, 0, 0);
        }
      }
      __builtin_amdgcn_s_setprio(0);
      if (kt0 + 63 > qw) {
#pragma unroll
        for (int kb = 0; kb < 2; kb++)
#pragma unroll
          for (int r = 0; r < 16; r++) {
            int key = kt0 + kb * 32 + (r & 3) + 8 * (r >> 2) + 4 * hi;
            if (key > myq) s[kb][r] = -1e30f;
          }
      }
      float tm = -1e30f;
#pragma unroll
      for (int kb = 0; kb < 2; kb++)
#pragma unroll
        for (int r = 0; r < 16; r++) tm = fmaxf(tm, s[kb][r]);
      tm = fmaxf(tm, __shfl_xor(tm, 32, 64));
      if (!__all(tm <= mi + 8.0f)) {          // defer-max: rescale only on growth
        float mnew = fmaxf(mi, tm);
        float alpha = exp2f(mi - mnew);
        li *= alpha;
#pragma unroll
        for (int d = 0; d < 4; d++)
#pragma unroll
          for (int r = 0; r < 16; r++) o[d][r] *= alpha;
        mi = mnew;
      }
      float p[32];
      float rs = 0.f;
#pragma unroll
      for (int kb = 0; kb < 2; kb++)
#pragma unroll
        for (int r = 0; r < 16; r++) {
          float e = exp2f(s[kb][r] - mi);
          p[kb * 16 + r] = e;
          rs += e;
        }
      li += rs;
#pragma unroll
      for (int ks = 0; ks < 4; ks++) {
        const int pb = ks * 8;
        unsigned A = pkbf(p[pb + 0], p[pb + 1]), B = pkbf(p[pb + 2], p[pb + 3]);
        unsigned C = pkbf(p[pb + 4], p[pb + 5]), D = pkbf(p[pb + 6], p[pb + 7]);
        unsigned Ax = __shfl_xor(A, 32, 64);
        unsigned Bx = __shfl_xor(B, 32, 64);
        unsigned Cx = __shfl_xor(C, 32, 64);
        unsigned Dx = __shfl_xor(D, 32, 64);
        union { bf16x8 v; unsigned u[4]; } pf;
        pf.u[0] = hi ? Cx : A;
        pf.u[1] = hi ? Dx : B;
        pf.u[2] = hi ? C : Ax;
        pf.u[3] = hi ? D : Bx;
        __builtin_amdgcn_s_setprio(1);
#pragma unroll
        for (int db = 0; db < 4; db++) {
          const bf16* vbase = &Vs[cur][(db * 32 + col) * 64];
          bf16x8 av = *(const bf16x8*)&vbase[((ks * 2 + hi) ^ rsw) * 8];
          o[db] = __builtin_amdgcn_mfma_f32_32x32x16_bf16(av, pf.v, o[db], 0, 0, 0);
        }
        __builtin_amdgcn_s_setprio(0);
      }
    }
    asm volatile("s_waitcnt vmcnt(0)" ::: "memory");
    __syncthreads();
  }

  li += __shfl_xor(li, 32, 64);
  float rinv = 1.0f / li;
  bf16* dst = attn + ((size_t)b * SEQ + qw + col) * HIDDEN + h * HD;
#pragma unroll
  for (int db = 0; db < 4; db++)
#pragma unroll
    for (int rr = 0; rr < 4; rr++) {
      bf16x4 ob;
#pragma unroll
      for (int j = 0; j < 4; j++) ob[j] = (bf16)(o[db][rr * 4 + j] * rinv);
      *(bf16x4*)&dst[db * 32 + rr * 8 + hi * 4] = ob;
    }
}

extern "C" void kernel_launch(void* const* d_in, const int* in_sizes, int n_in,
                              void* d_out, int out_size, void* d_ws, size_t ws_size,
                              hipStream_t stream) {
  const float* hidden = (const float*)d_in[0];
  const float* cosp   = (const float*)d_in[1];
  const float* sinp   = (const float*)d_in[2];
  const float* Wq = (const float*)d_in[4];
  const float* bq = (const float*)d_in[5];
  const float* Wk = (const float*)d_in[6];
  const float* bk = (const float*)d_in[7];
  const float* Wv = (const float*)d_in[8];
  const float* bv = (const float*)d_in[9];
  const float* Wo = (const float*)d_in[10];
  float* out = (float*)d_out;

  char* ws = (char*)d_ws;
  size_t off = 0;
  auto alloc = [&](size_t bytes) {
    char* p = ws + off;
    off += (bytes + 255) & ~(size_t)255;
    return p;
  };
  const size_t M = 4096;
  bf16* hb  = (bf16*)alloc(M * HIDDEN * 2);
  bf16* wqb = (bf16*)alloc((size_t)3584 * 3584 * 2);
  bf16* wkb = (bf16*)alloc((size_t)512 * 3584 * 2);
  bf16* wvb = (bf16*)alloc((size_t)512 * 3584 * 2);
  bf16* wob = (bf16*)alloc((size_t)3584 * 3584 * 2);
  bf16* Qb  = (bf16*)alloc((size_t)2 * NHEADS * SEQ * HD * 2);
  bf16* Kb  = (bf16*)alloc((size_t)2 * NKV * SEQ * HD * 2);
  bf16* Vt  = (bf16*)alloc((size_t)2 * NKV * SEQ * HD * 2);
  bf16* attn = hb;  // hidden dead after QKV GEMM

  f2bf_kernel<<<(4096 * 3584 / 8 + 255) / 256, 256, 0, stream>>>(hidden, hb, 4096 * 3584 / 8);
  f2bf_kernel<<<(3584 * 3584 / 8 + 255) / 256, 256, 0, stream>>>(Wq, wqb, 3584 * 3584 / 8);
  f2bf_kernel<<<(512 * 3584 / 8 + 255) / 256, 256, 0, stream>>>(Wk, wkb, 512 * 3584 / 8);
  f2bf_kernel<<<(512 * 3584 / 8 + 255) / 256, 256, 0, stream>>>(Wv, wvb, 512 * 3584 / 8);
  f2bf_kernel<<<(3584 * 3584 / 8 + 255) / 256, 256, 0, stream>>>(Wo, wob, 3584 * 3584 / 8);

  gemm_kernel<1><<<dim3(36, 32), 256, 0, stream>>>(hb, wqb, wkb, wvb, bq, bk, bv,
                                                   cosp, sinp,
                                                   nullptr, Qb, Kb, Vt);
  flash_kernel<<<dim3(16, 28, 2), 256, 0, stream>>>(Qb, Kb, Vt, attn);
  gemm_kernel<0><<<dim3(28, 32), 256, 0, stream>>>(attn, wob, nullptr, nullptr,
                                                   nullptr, nullptr, nullptr,
                                                   nullptr, nullptr,
                                                   out, nullptr, nullptr, nullptr);
}